// Round 13
// baseline (210.941 us; speedup 1.0000x reference)
//
#include <hip/hip_runtime.h>
#include <hip/hip_bf16.h>

// Linear attention (BaseMultiHeadAttention_21105469292684)
// M=16, N=2048, C=512, H=8, D=64.
//   K0 : weights fp32 -> bf16 transposed WT[col][k]            [r10 verbatim]
//   K1 : Q/K/V fused proj+softmax: BM=128 x BN=256, BK=64, 8 K-steps,
//        single-buf, 2 barriers/step (r7 mechanics, half the drain points).
//        A: fp32->reg(T14 prefetch)->bf16 As[128][72]. B: gload_lds + 8-chunk involution.
//   K2 : kv partials = K_h^T V_h over n-chunks                 [r10 verbatim]
//   K3 : WfusedT = blockdiag(kv) @ Wo                          [r10 verbatim]
//   K4 : out = Q @ Wfused[m] + bo, single-buf all-glds         [r10 verbatim]

typedef __bf16 bf16;
typedef __bf16 bf16x8 __attribute__((ext_vector_type(8)));
typedef __bf16 bf16x4 __attribute__((ext_vector_type(4)));
typedef float  f32x4  __attribute__((ext_vector_type(4)));

#define MFMA16(a, b, c) __builtin_amdgcn_mfma_f32_16x16x32_bf16((a), (b), (c), 0, 0, 0)

__device__ inline bf16x8 cvt8(float4 a, float4 b) {
  bf16x8 h;
  h[0] = (bf16)a.x; h[1] = (bf16)a.y; h[2] = (bf16)a.z; h[3] = (bf16)a.w;
  h[4] = (bf16)b.x; h[5] = (bf16)b.y; h[6] = (bf16)b.z; h[7] = (bf16)b.w;
  return h;
}

__device__ inline void glds16(const void* g, void* l) {
  __builtin_amdgcn_global_load_lds((const __attribute__((address_space(1))) void*)g,
                                   (__attribute__((address_space(3))) void*)l, 16, 0, 0);
}

// ---------------- K0: transpose + convert weights (512x512 each) ----------------
__global__ __launch_bounds__(256) void k_prep(const float* __restrict__ w0, const float* __restrict__ w1,
                                              const float* __restrict__ w2, const float* __restrict__ w3,
                                              bf16* __restrict__ t0, bf16* __restrict__ t1,
                                              bf16* __restrict__ t2, bf16* __restrict__ t3)
{
  const float* W = (blockIdx.z == 0) ? w0 : (blockIdx.z == 1) ? w1 : (blockIdx.z == 2) ? w2 : w3;
  bf16*        T = (blockIdx.z == 0) ? t0 : (blockIdx.z == 1) ? t1 : (blockIdx.z == 2) ? t2 : t3;
  __shared__ float lds[64][68];
  const int t = threadIdx.x;
  const int r = t >> 2, c0 = (t & 3) << 4;
  const float* src = W + (size_t)(blockIdx.x * 64 + r) * 512 + blockIdx.y * 64 + c0;
  float4 f0 = ((const float4*)src)[0];
  float4 f1 = ((const float4*)src)[1];
  float4 f2 = ((const float4*)src)[2];
  float4 f3 = ((const float4*)src)[3];
  *(float4*)&lds[r][c0 + 0]  = f0;
  *(float4*)&lds[r][c0 + 4]  = f1;
  *(float4*)&lds[r][c0 + 8]  = f2;
  *(float4*)&lds[r][c0 + 12] = f3;
  __syncthreads();
  bf16 v[16];
#pragma unroll
  for (int s = 0; s < 16; ++s) v[s] = (bf16)lds[c0 + s][r];
  bf16* dst = T + (size_t)(blockIdx.y * 64 + r) * 512 + blockIdx.x * 64 + c0;
  *(bf16x8*)&dst[0] = *(bf16x8*)&v[0];
  *(bf16x8*)&dst[8] = *(bf16x8*)&v[8];
}

// ---------------- K1: fused projection + per-head softmax (BK=64, 8 steps) ----------------
// 1536 blocks (3 proj x 256 rowb x 2 cb), 512 thr = 8 waves (2x4), wave 64x64.
// A: thread t stages row t>>2, 16 k-elems at (t&3)*16 (4 float4 -> cvt -> 2 b128 writes).
// B: gload_lds into linear Bs[256][64]; slot s at row r holds chunk s^(r&7);
//    read chunk m=ksub*4+g at slot m^(li&7).
__global__ __launch_bounds__(512) void k_qkv(const float* __restrict__ xq, const float* __restrict__ xk,
                                             const float* __restrict__ xv,
                                             const bf16* __restrict__ WqT, const bf16* __restrict__ WkT,
                                             const bf16* __restrict__ WvT,
                                             bf16* __restrict__ Qo, bf16* __restrict__ Ko,
                                             bf16* __restrict__ Vo)
{
  const int wg = blockIdx.x;
  const int o  = (wg & 7) * 192 + (wg >> 3);    // 1536 = 192*8, bijective XCD chunking
  const int proj = o >> 9;
  const int rem  = o & 511;
  const int rb = rem >> 1, cb = rem & 1;

  const float* X  = (proj == 0) ? xq  : (proj == 1) ? xk  : xv;
  const bf16*  WT = (proj == 0) ? WqT : (proj == 1) ? WkT : WvT;
  bf16*       OUT = (proj == 0) ? Qo  : (proj == 1) ? Ko  : Vo;

  __shared__ bf16 As[128][72];    // 18 KB (pad-72: 2-way banks on write & read)
  __shared__ bf16 Bs[256 * 64];   // 32 KB, linear (gload_lds dest)

  const int t = threadIdx.x;
  const int lane = t & 63, w = t >> 6;
  const int wr = w >> 2, wc = w & 3;
  const int g = lane >> 4, li = lane & 15;
  const size_t arow = (size_t)rb * 128;

  // A staging: thread -> row t>>2, 16 k-elems at col (t&3)*16
  const int ar = t >> 2, ac = (t & 3) << 4;
  const float* xp = X + (arow + ar) * 512 + ac;

  // B staging: wave w stages rows w*32..+32 in 4 issues of 8 rows;
  // lane l -> row w*32 + j*8 + (l>>3), slot l&7 holds source chunk (l&7)^((l>>3)&7)
  const bf16* bsrc = WT + (size_t)(cb * 256 + w * 32 + (lane >> 3)) * 512
                        + (((lane & 7) ^ ((lane >> 3) & 7)) << 3);
  char* bdst = (char*)&Bs[0] + w * 4096;        // 32 rows x 128 B per wave

  f32x4 acc[4][4] = {};
  float4 xa[4];
#pragma unroll
  for (int i = 0; i < 4; ++i) xa[i] = ((const float4*)xp)[i];   // kt=0 A (64 B)

  for (int kt = 0; kt < 8; ++kt) {
    __syncthreads();                            // (1) readers done with prev tile
    // write A (cvt in reg, 2x 16B ds_write)
    *(bf16x8*)&As[ar][ac]     = cvt8(xa[0], xa[1]);
    *(bf16x8*)&As[ar][ac + 8] = cvt8(xa[2], xa[3]);
#pragma unroll
    for (int j = 0; j < 4; ++j)                 // stage B slice (4 x 1KB per wave)
      glds16(bsrc + (size_t)j * 8 * 512 + kt * 64, bdst + j * 1024);
    __syncthreads();                            // (2) staging visible (drain)
    if (kt < 7) {                               // T14: next A flies under compute
#pragma unroll
      for (int i = 0; i < 4; ++i) xa[i] = ((const float4*)(xp + (kt + 1) * 64))[i];
    }
#pragma unroll
    for (int ksub = 0; ksub < 2; ++ksub) {
      bf16x8 af[4], bfr[4];
#pragma unroll
      for (int rt = 0; rt < 4; ++rt)
        af[rt] = *(const bf16x8*)&As[wr * 64 + rt * 16 + li][ksub * 32 + g * 8];
#pragma unroll
      for (int ct = 0; ct < 4; ++ct) {
        const int c2 = wc * 64 + ct * 16 + li;
        bfr[ct] = *(const bf16x8*)&Bs[c2 * 64 + (((ksub * 4 + g) ^ (li & 7)) << 3)];
      }
#pragma unroll
      for (int rt = 0; rt < 4; ++rt)
#pragma unroll
        for (int ct = 0; ct < 4; ++ct)
          acc[rt][ct] = MFMA16(af[rt], bfr[ct], acc[rt][ct]);
    }
  }

  // epilogue: softmax over this wave's head (64 cols = 4 ct x 16 li)
#pragma unroll
  for (int rt = 0; rt < 4; ++rt) {
#pragma unroll
    for (int q = 0; q < 4; ++q) {
      float v0 = acc[rt][0][q], v1 = acc[rt][1][q], v2 = acc[rt][2][q], v3 = acc[rt][3][q];
      if (proj < 2) {
        float mx = fmaxf(fmaxf(v0, v1), fmaxf(v2, v3));
        mx = fmaxf(mx, __shfl_xor(mx, 1));
        mx = fmaxf(mx, __shfl_xor(mx, 2));
        mx = fmaxf(mx, __shfl_xor(mx, 4));
        mx = fmaxf(mx, __shfl_xor(mx, 8));
        v0 = __expf(v0 - mx); v1 = __expf(v1 - mx); v2 = __expf(v2 - mx); v3 = __expf(v3 - mx);
        float s = v0 + v1 + v2 + v3;
        s += __shfl_xor(s, 1); s += __shfl_xor(s, 2); s += __shfl_xor(s, 4); s += __shfl_xor(s, 8);
        const float inv = (proj == 0 ? 0.125f : 1.0f) / s;
        v0 *= inv; v1 *= inv; v2 *= inv; v3 *= inv;
      }
      bf16* op = OUT + (arow + wr * 64 + rt * 16 + g * 4 + q) * 512 + cb * 256 + wc * 64 + li;
      op[0] = (bf16)v0; op[16] = (bf16)v1; op[32] = (bf16)v2; op[48] = (bf16)v3;
    }
  }
}

// ---------------- K2: kv partials = K_h^T V_h over an n-chunk [r10] ----------------
__global__ __launch_bounds__(256) void k_kv(const bf16* __restrict__ K, const bf16* __restrict__ V,
                                            float* __restrict__ kvp)
{
  const int mh = blockIdx.x, m = mh >> 3, h = mh & 7;
  const int ns = blockIdx.y;
  __shared__ bf16 Kt[64][40];
  __shared__ bf16 Vt[64][40];
  const int t = threadIdx.x, lane = t & 63, wave = t >> 6;
  const int dq = wave >> 1, eq = wave & 1;
  const int g = lane >> 4, li = lane & 15;
  const int tn = t & 31, d0 = (t >> 5) << 3;
  const size_t rowbase = (size_t)m * 2048 + ns * 512;

  f32x4 acc[2][2] = {};

  for (int nt = 0; nt < 16; ++nt) {
    __syncthreads();
    {
      bf16x8 kr = *(const bf16x8*)(K + (rowbase + nt * 32 + tn) * 512 + h * 64 + d0);
      bf16x8 vr = *(const bf16x8*)(V + (rowbase + nt * 32 + tn) * 512 + h * 64 + d0);
#pragma unroll
      for (int j = 0; j < 8; ++j) Kt[d0 + j][tn] = kr[j];
#pragma unroll
      for (int j = 0; j < 8; ++j) Vt[d0 + j][tn] = vr[j];
    }
    __syncthreads();
    bf16x8 af[2], bfr[2];
#pragma unroll
    for (int dt = 0; dt < 2; ++dt) af[dt]  = *(const bf16x8*)&Kt[dq * 32 + dt * 16 + li][g * 8];
#pragma unroll
    for (int et = 0; et < 2; ++et) bfr[et] = *(const bf16x8*)&Vt[eq * 32 + et * 16 + li][g * 8];
#pragma unroll
    for (int dt = 0; dt < 2; ++dt)
#pragma unroll
      for (int et = 0; et < 2; ++et)
        acc[dt][et] = MFMA16(af[dt], bfr[et], acc[dt][et]);
  }

  float* o = kvp + ((size_t)mh * 4 + ns) * 4096;
#pragma unroll
  for (int dt = 0; dt < 2; ++dt)
#pragma unroll
    for (int et = 0; et < 2; ++et)
#pragma unroll
      for (int q = 0; q < 4; ++q) {
        const int d = dq * 32 + dt * 16 + g * 4 + q;
        const int e = eq * 32 + et * 16 + li;
        o[d * 64 + e] = acc[dt][et][q];
      }
}

// ---------------- K3: WfusedT[m][c][r=h*64+d] = sum_e kv[d][e] * WoT[c][h*64+e] [r10] ----------------
__global__ __launch_bounds__(512) void k_wfused(const float* __restrict__ kvp, const bf16* __restrict__ WoT,
                                                bf16* __restrict__ WfT)
{
  const int mh = blockIdx.x, m = mh >> 3, h = mh & 7;
  __shared__ bf16 kvs[64][72];
  const int t = threadIdx.x, lane = t & 63, wave = t >> 6;
  const int g = lane >> 4, li = lane & 15;
  {
    const int d = t >> 3, e0 = (t & 7) << 3;
    const float* p = kvp + (size_t)mh * 16384 + d * 64 + e0;
#pragma unroll
    for (int j = 0; j < 8; ++j) {
      float s = p[j] + p[4096 + j] + p[8192 + j] + p[12288 + j];
      kvs[d][e0 + j] = (bf16)s;
    }
  }
  __syncthreads();
  f32x4 acc[4][4] = {};
#pragma unroll
  for (int kk = 0; kk < 2; ++kk) {
    bf16x8 af[4], bfr[4];
#pragma unroll
    for (int rt = 0; rt < 4; ++rt) {
      const int c = wave * 64 + rt * 16 + li;
      af[rt] = *(const bf16x8*)(WoT + (size_t)c * 512 + h * 64 + kk * 32 + g * 8);
    }
#pragma unroll
    for (int ct = 0; ct < 4; ++ct)
      bfr[ct] = *(const bf16x8*)&kvs[ct * 16 + li][kk * 32 + g * 8];
#pragma unroll
    for (int rt = 0; rt < 4; ++rt)
#pragma unroll
      for (int ct = 0; ct < 4; ++ct)
        acc[rt][ct] = MFMA16(af[rt], bfr[ct], acc[rt][ct]);
  }
  bf16* o = WfT + (size_t)m * 262144;
#pragma unroll
  for (int rt = 0; rt < 4; ++rt)
#pragma unroll
    for (int ct = 0; ct < 4; ++ct)
#pragma unroll
      for (int q = 0; q < 4; ++q) {
        const int c = wave * 64 + rt * 16 + g * 4 + q;
        const int r = h * 64 + ct * 16 + li;
        o[(size_t)c * 512 + r] = (bf16)acc[rt][ct][q];
      }
}

// ---------------- K4: out = Q @ Wfused[m] + bo (BM=128, BN=256, all-glds, single-buf) [r10] ----------------
__global__ __launch_bounds__(512) void k_out(const bf16* __restrict__ Q, const bf16* __restrict__ WfT,
                                             const float* __restrict__ bo, float* __restrict__ out)
{
  const int wg = blockIdx.x;
  const int o  = (wg & 7) * 64 + (wg >> 3);     // 512 = 64*8, bijective
  const int rb = o >> 1, cb = o & 1;
  const int m  = rb >> 4;                       // 16 row-blocks (128 rows) per m
  const bf16* Bm = WfT + (size_t)m * 262144;

  __shared__ bf16 As2[128 * 32];   // 8 KB, linear
  __shared__ bf16 Bs2[256 * 32];   // 16 KB, linear

  const int t = threadIdx.x, lane = t & 63, w = t >> 6;
  const int wr = w >> 2, wc = w & 3;
  const int g = lane >> 4, li = lane & 15;
  const size_t arow = (size_t)rb * 128;

  const int schunk = ((lane & 3) ^ ((lane >> 3) & 3)) << 3;
  const bf16* asrc = Q + (arow + w * 16 + (lane >> 2)) * 512 + schunk;
  const bf16* bsrc = Bm + (size_t)(cb * 256 + w * 32 + (lane >> 2)) * 512 + schunk;
  char* adst = (char*)&As2[0] + w * 1024;
  char* bdst = (char*)&Bs2[0] + w * 2048;
  const int slot = g ^ ((li >> 1) & 3);

  f32x4 acc[4][4] = {};

  for (int kt = 0; kt < 16; ++kt) {
    __syncthreads();
    glds16(asrc + kt * 32, adst);
#pragma unroll
    for (int j = 0; j < 2; ++j)
      glds16(bsrc + (size_t)j * 16 * 512 + kt * 32, bdst + j * 1024);
    __syncthreads();
    bf16x8 af[4], bfr[4];
#pragma unroll
    for (int rt = 0; rt < 4; ++rt)
      af[rt] = *(const bf16x8*)&As2[(wr * 64 + rt * 16 + li) * 32 + slot * 8];
#pragma unroll
    for (int ct = 0; ct < 4; ++ct)
      bfr[ct] = *(const bf16x8*)&Bs2[(wc * 64 + ct * 16 + li) * 32 + slot * 8];
#pragma unroll
    for (int rt = 0; rt < 4; ++rt)
#pragma unroll
      for (int ct = 0; ct < 4; ++ct)
        acc[rt][ct] = MFMA16(af[rt], bfr[ct], acc[rt][ct]);
  }

  float bv[4];
#pragma unroll
  for (int ct = 0; ct < 4; ++ct) bv[ct] = bo[cb * 256 + wc * 64 + ct * 16 + li];
#pragma unroll
  for (int rt = 0; rt < 4; ++rt)
#pragma unroll
    for (int q = 0; q < 4; ++q) {
      float* op = out + (arow + wr * 64 + rt * 16 + g * 4 + q) * 512 + cb * 256 + wc * 64 + li;
      op[0]  = acc[rt][0][q] + bv[0];
      op[16] = acc[rt][1][q] + bv[1];
      op[32] = acc[rt][2][q] + bv[2];
      op[48] = acc[rt][3][q] + bv[3];
    }
}

// ---------------- host ----------------
extern "C" void kernel_launch(void* const* d_in, const int* in_sizes, int n_in,
                              void* d_out, int out_size, void* d_ws, size_t ws_size,
                              hipStream_t stream)
{
  const float* xq = (const float*)d_in[0];
  const float* xk = (const float*)d_in[1];
  const float* xv = (const float*)d_in[2];
  const float* Wq = (const float*)d_in[3];
  const float* Wk = (const float*)d_in[4];
  const float* Wv = (const float*)d_in[5];
  const float* Wo = (const float*)d_in[6];
  const float* bo = (const float*)d_in[7];
  float* out = (float*)d_out;

  char* ws = (char*)d_ws;
  const size_t WT_BYTES  = 512 * 512 * 2;           // 512 KiB each
  const size_t QKV_BYTES = (size_t)32768 * 512 * 2; // 32 MiB each
  bf16*  WqT = (bf16*)(ws);
  bf16*  WkT = (bf16*)(ws + WT_BYTES);
  bf16*  WvT = (bf16*)(ws + 2 * WT_BYTES);
  bf16*  WoT = (bf16*)(ws + 3 * WT_BYTES);
  bf16*  Qb  = (bf16*)(ws + 4 * WT_BYTES);
  bf16*  Kb  = (bf16*)(ws + 4 * WT_BYTES + QKV_BYTES);
  bf16*  Vb  = (bf16*)(ws + 4 * WT_BYTES + 2 * QKV_BYTES);
  float* kvp = (float*)(ws + 4 * WT_BYTES + 3 * QKV_BYTES);  // 8 MiB
  bf16*  WfT = Kb;  // overlay: Kb dead after k_kv

  k_prep  <<<dim3(8, 8, 4), 256, 0, stream>>>(Wq, Wk, Wv, Wo, WqT, WkT, WvT, WoT);
  k_qkv   <<<dim3(1536),    512, 0, stream>>>(xq, xk, xv, WqT, WkT, WvT, Qb, Kb, Vb);
  k_kv    <<<dim3(128, 4),  256, 0, stream>>>(Kb, Vb, kvp);
  k_wfused<<<dim3(128),     512, 0, stream>>>(kvp, WoT, WfT);
  k_out   <<<dim3(512),     512, 0, stream>>>(Qb, WfT, bo, out);
}

// Round 14
// 163.739 us; speedup vs baseline: 1.2883x; 1.2883x over previous
//
#include <hip/hip_runtime.h>
#include <hip/hip_bf16.h>

// Linear attention (BaseMultiHeadAttention_21105469292684)
// M=16, N=2048, C=512, H=8, D=64.
// REVERT to measured-best (round 10, 165.24 us total):
//   K0 : weights fp32 -> bf16 transposed WT[col][k]
//   K1 : Q/K/V = softmax-ish(x @ W): BM=128 x BN=256, 8 waves (2x4), wave 64x64,
//        BK=32, single-buf, 2 barriers/step, A reg-staged fp32->bf16 pad-40,
//        B gload_lds + involution swizzle, T14 A-prefetch.
//   K2 : kv partials = K_h^T V_h over n-chunks (fp32)
//   K3 : WfusedT[m][c][r] = sum_e kv[m,h,d,e] * Wo[h*64+e][c]  (bf16)
//   K4 : out = Q @ Wfused[m] + bo: same geometry, both operands gload_lds, single-buf.

typedef __bf16 bf16;
typedef __bf16 bf16x8 __attribute__((ext_vector_type(8)));
typedef __bf16 bf16x4 __attribute__((ext_vector_type(4)));
typedef float  f32x4  __attribute__((ext_vector_type(4)));

#define MFMA16(a, b, c) __builtin_amdgcn_mfma_f32_16x16x32_bf16((a), (b), (c), 0, 0, 0)

__device__ inline bf16x8 cvt8(float4 a, float4 b) {
  bf16x8 h;
  h[0] = (bf16)a.x; h[1] = (bf16)a.y; h[2] = (bf16)a.z; h[3] = (bf16)a.w;
  h[4] = (bf16)b.x; h[5] = (bf16)b.y; h[6] = (bf16)b.z; h[7] = (bf16)b.w;
  return h;
}

__device__ inline void glds16(const void* g, void* l) {
  __builtin_amdgcn_global_load_lds((const __attribute__((address_space(1))) void*)g,
                                   (__attribute__((address_space(3))) void*)l, 16, 0, 0);
}

// ---------------- K0: transpose + convert weights (512x512 each) ----------------
__global__ __launch_bounds__(256) void k_prep(const float* __restrict__ w0, const float* __restrict__ w1,
                                              const float* __restrict__ w2, const float* __restrict__ w3,
                                              bf16* __restrict__ t0, bf16* __restrict__ t1,
                                              bf16* __restrict__ t2, bf16* __restrict__ t3)
{
  const float* W = (blockIdx.z == 0) ? w0 : (blockIdx.z == 1) ? w1 : (blockIdx.z == 2) ? w2 : w3;
  bf16*        T = (blockIdx.z == 0) ? t0 : (blockIdx.z == 1) ? t1 : (blockIdx.z == 2) ? t2 : t3;
  __shared__ float lds[64][68];
  const int t = threadIdx.x;
  const int r = t >> 2, c0 = (t & 3) << 4;
  const float* src = W + (size_t)(blockIdx.x * 64 + r) * 512 + blockIdx.y * 64 + c0;
  float4 f0 = ((const float4*)src)[0];
  float4 f1 = ((const float4*)src)[1];
  float4 f2 = ((const float4*)src)[2];
  float4 f3 = ((const float4*)src)[3];
  *(float4*)&lds[r][c0 + 0]  = f0;
  *(float4*)&lds[r][c0 + 4]  = f1;
  *(float4*)&lds[r][c0 + 8]  = f2;
  *(float4*)&lds[r][c0 + 12] = f3;
  __syncthreads();
  bf16 v[16];
#pragma unroll
  for (int s = 0; s < 16; ++s) v[s] = (bf16)lds[c0 + s][r];
  bf16* dst = T + (size_t)(blockIdx.y * 64 + r) * 512 + blockIdx.x * 64 + c0;
  *(bf16x8*)&dst[0] = *(bf16x8*)&v[0];
  *(bf16x8*)&dst[8] = *(bf16x8*)&v[8];
}

// ---------------- K1: fused projection + per-head softmax (BM=128, BN=256) ----------------
// 1536 blocks (3 proj x 256 rowb x 2 cb), 512 thr = 8 waves (2 row x 4 col), wave 64x64.
__global__ __launch_bounds__(512) void k_qkv(const float* __restrict__ xq, const float* __restrict__ xk,
                                             const float* __restrict__ xv,
                                             const bf16* __restrict__ WqT, const bf16* __restrict__ WkT,
                                             const bf16* __restrict__ WvT,
                                             bf16* __restrict__ Qo, bf16* __restrict__ Ko,
                                             bf16* __restrict__ Vo)
{
  const int wg = blockIdx.x;
  const int o  = (wg & 7) * 192 + (wg >> 3);    // 1536 = 192*8, bijective XCD chunking
  const int proj = o >> 9;                      // 512 blocks per projection
  const int rem  = o & 511;
  const int rb = rem >> 1, cb = rem & 1;        // (rb,cb) adjacent -> same XCD (A L2 reuse)

  const float* X  = (proj == 0) ? xq  : (proj == 1) ? xk  : xv;
  const bf16*  WT = (proj == 0) ? WqT : (proj == 1) ? WkT : WvT;
  bf16*       OUT = (proj == 0) ? Qo  : (proj == 1) ? Ko  : Vo;

  __shared__ bf16 As[128][40];    // 10 KB
  __shared__ bf16 Bs[256 * 32];   // 16 KB, linear (gload_lds dest)

  const int t = threadIdx.x;
  const int lane = t & 63, w = t >> 6;
  const int wr = w >> 2, wc = w & 3;
  const int g = lane >> 4, li = lane & 15;
  const size_t arow = (size_t)rb * 128;

  // A staging: thread -> row t>>2, 8 floats at col (t&3)*8
  const int ar = t >> 2, ac = (t & 3) << 3;
  const float* xp = X + (arow + ar) * 512 + ac;

  // B staging: wave w stages rows w*32..+32; lane l -> row w*32+(l>>2),
  // slot l&3 holds source chunk (l&3)^((l>>3)&3)  (involution with (row>>1)&3)
  const bf16* bsrc = WT + (size_t)(cb * 256 + w * 32 + (lane >> 2)) * 512
                        + (((lane & 3) ^ ((lane >> 3) & 3)) << 3);
  char* bdst = (char*)&Bs[0] + w * 2048;        // wave-uniform dest base (32 rows = 2 KB)
  const int bslot = g ^ ((li >> 1) & 3);        // read-side slot

  f32x4 acc[4][4] = {};
  float4 xa0 = ((const float4*)xp)[0];          // kt=0 A fragment (8 floats)
  float4 xa1 = ((const float4*)xp)[1];

  for (int kt = 0; kt < 16; ++kt) {
    __syncthreads();                            // (1) readers done with prev tiles
    *(bf16x8*)&As[ar][ac] = cvt8(xa0, xa1);     // write A (cvt in reg, 16B ds_write)
#pragma unroll
    for (int j = 0; j < 2; ++j)                 // stage B slice (2 x 1KB per wave)
      glds16(bsrc + (size_t)j * 16 * 512 + kt * 32, bdst + j * 1024);
    __syncthreads();                            // (2) staging visible
    if (kt < 15) {                              // T14: next A-load flies under compute
      xa0 = ((const float4*)(xp + (kt + 1) * 32))[0];
      xa1 = ((const float4*)(xp + (kt + 1) * 32))[1];
    }
    bf16x8 af[4], bfr[4];
#pragma unroll
    for (int rt = 0; rt < 4; ++rt)
      af[rt] = *(const bf16x8*)&As[wr * 64 + rt * 16 + li][g * 8];
#pragma unroll
    for (int ct = 0; ct < 4; ++ct)
      bfr[ct] = *(const bf16x8*)&Bs[(wc * 64 + ct * 16 + li) * 32 + bslot * 8];
#pragma unroll
    for (int rt = 0; rt < 4; ++rt)
#pragma unroll
      for (int ct = 0; ct < 4; ++ct)
        acc[rt][ct] = MFMA16(af[rt], bfr[ct], acc[rt][ct]);
  }

  // epilogue: softmax over this wave's head (64 cols = 4 ct x 16 li)
#pragma unroll
  for (int rt = 0; rt < 4; ++rt) {
#pragma unroll
    for (int q = 0; q < 4; ++q) {
      float v0 = acc[rt][0][q], v1 = acc[rt][1][q], v2 = acc[rt][2][q], v3 = acc[rt][3][q];
      if (proj < 2) {
        float mx = fmaxf(fmaxf(v0, v1), fmaxf(v2, v3));
        mx = fmaxf(mx, __shfl_xor(mx, 1));
        mx = fmaxf(mx, __shfl_xor(mx, 2));
        mx = fmaxf(mx, __shfl_xor(mx, 4));
        mx = fmaxf(mx, __shfl_xor(mx, 8));
        v0 = __expf(v0 - mx); v1 = __expf(v1 - mx); v2 = __expf(v2 - mx); v3 = __expf(v3 - mx);
        float s = v0 + v1 + v2 + v3;
        s += __shfl_xor(s, 1); s += __shfl_xor(s, 2); s += __shfl_xor(s, 4); s += __shfl_xor(s, 8);
        const float inv = (proj == 0 ? 0.125f : 1.0f) / s;
        v0 *= inv; v1 *= inv; v2 *= inv; v3 *= inv;
      }
      bf16* op = OUT + (arow + wr * 64 + rt * 16 + g * 4 + q) * 512 + cb * 256 + wc * 64 + li;
      op[0] = (bf16)v0; op[16] = (bf16)v1; op[32] = (bf16)v2; op[48] = (bf16)v3;
    }
  }
}

// ---------------- K2: kv partials = K_h^T V_h over an n-chunk ----------------
__global__ __launch_bounds__(256) void k_kv(const bf16* __restrict__ K, const bf16* __restrict__ V,
                                            float* __restrict__ kvp)
{
  const int mh = blockIdx.x, m = mh >> 3, h = mh & 7;
  const int ns = blockIdx.y;
  __shared__ bf16 Kt[64][40];
  __shared__ bf16 Vt[64][40];
  const int t = threadIdx.x, lane = t & 63, wave = t >> 6;
  const int dq = wave >> 1, eq = wave & 1;
  const int g = lane >> 4, li = lane & 15;
  const int tn = t & 31, d0 = (t >> 5) << 3;
  const size_t rowbase = (size_t)m * 2048 + ns * 512;

  f32x4 acc[2][2] = {};

  for (int nt = 0; nt < 16; ++nt) {
    __syncthreads();
    {
      bf16x8 kr = *(const bf16x8*)(K + (rowbase + nt * 32 + tn) * 512 + h * 64 + d0);
      bf16x8 vr = *(const bf16x8*)(V + (rowbase + nt * 32 + tn) * 512 + h * 64 + d0);
#pragma unroll
      for (int j = 0; j < 8; ++j) Kt[d0 + j][tn] = kr[j];
#pragma unroll
      for (int j = 0; j < 8; ++j) Vt[d0 + j][tn] = vr[j];
    }
    __syncthreads();
    bf16x8 af[2], bfr[2];
#pragma unroll
    for (int dt = 0; dt < 2; ++dt) af[dt]  = *(const bf16x8*)&Kt[dq * 32 + dt * 16 + li][g * 8];
#pragma unroll
    for (int et = 0; et < 2; ++et) bfr[et] = *(const bf16x8*)&Vt[eq * 32 + et * 16 + li][g * 8];
#pragma unroll
    for (int dt = 0; dt < 2; ++dt)
#pragma unroll
      for (int et = 0; et < 2; ++et)
        acc[dt][et] = MFMA16(af[dt], bfr[et], acc[dt][et]);
  }

  float* o = kvp + ((size_t)mh * 4 + ns) * 4096;
#pragma unroll
  for (int dt = 0; dt < 2; ++dt)
#pragma unroll
    for (int et = 0; et < 2; ++et)
#pragma unroll
      for (int q = 0; q < 4; ++q) {
        const int d = dq * 32 + dt * 16 + g * 4 + q;
        const int e = eq * 32 + et * 16 + li;
        o[d * 64 + e] = acc[dt][et][q];
      }
}

// ---------------- K3: WfusedT[m][c][r=h*64+d] = sum_e kv[d][e] * WoT[c][h*64+e] ----------------
__global__ __launch_bounds__(512) void k_wfused(const float* __restrict__ kvp, const bf16* __restrict__ WoT,
                                                bf16* __restrict__ WfT)
{
  const int mh = blockIdx.x, m = mh >> 3, h = mh & 7;
  __shared__ bf16 kvs[64][72];
  const int t = threadIdx.x, lane = t & 63, wave = t >> 6;
  const int g = lane >> 4, li = lane & 15;
  {
    const int d = t >> 3, e0 = (t & 7) << 3;
    const float* p = kvp + (size_t)mh * 16384 + d * 64 + e0;
#pragma unroll
    for (int j = 0; j < 8; ++j) {
      float s = p[j] + p[4096 + j] + p[8192 + j] + p[12288 + j];
      kvs[d][e0 + j] = (bf16)s;
    }
  }
  __syncthreads();
  f32x4 acc[4][4] = {};
#pragma unroll
  for (int kk = 0; kk < 2; ++kk) {
    bf16x8 af[4], bfr[4];
#pragma unroll
    for (int rt = 0; rt < 4; ++rt) {
      const int c = wave * 64 + rt * 16 + li;
      af[rt] = *(const bf16x8*)(WoT + (size_t)c * 512 + h * 64 + kk * 32 + g * 8);
    }
#pragma unroll
    for (int ct = 0; ct < 4; ++ct)
      bfr[ct] = *(const bf16x8*)&kvs[ct * 16 + li][kk * 32 + g * 8];
#pragma unroll
    for (int rt = 0; rt < 4; ++rt)
#pragma unroll
      for (int ct = 0; ct < 4; ++ct)
        acc[rt][ct] = MFMA16(af[rt], bfr[ct], acc[rt][ct]);
  }
  bf16* o = WfT + (size_t)m * 262144;
#pragma unroll
  for (int rt = 0; rt < 4; ++rt)
#pragma unroll
    for (int ct = 0; ct < 4; ++ct)
#pragma unroll
      for (int q = 0; q < 4; ++q) {
        const int c = wave * 64 + rt * 16 + g * 4 + q;
        const int r = h * 64 + ct * 16 + li;
        o[(size_t)c * 512 + r] = (bf16)acc[rt][ct][q];
      }
}

// ---------------- K4: out = Q @ Wfused[m] + bo (BM=128, BN=256, all-glds) ----------------
__global__ __launch_bounds__(512) void k_out(const bf16* __restrict__ Q, const bf16* __restrict__ WfT,
                                             const float* __restrict__ bo, float* __restrict__ out)
{
  const int wg = blockIdx.x;
  const int o  = (wg & 7) * 64 + (wg >> 3);     // 512 = 64*8, bijective
  const int rb = o >> 1, cb = o & 1;
  const int m  = rb >> 4;                       // 16 row-blocks (128 rows) per m
  const bf16* Bm = WfT + (size_t)m * 262144;

  __shared__ bf16 As2[128 * 32];   // 8 KB, linear
  __shared__ bf16 Bs2[256 * 32];   // 16 KB, linear

  const int t = threadIdx.x, lane = t & 63, w = t >> 6;
  const int wr = w >> 2, wc = w & 3;
  const int g = lane >> 4, li = lane & 15;
  const size_t arow = (size_t)rb * 128;

  const int schunk = ((lane & 3) ^ ((lane >> 3) & 3)) << 3;
  const bf16* asrc = Q + (arow + w * 16 + (lane >> 2)) * 512 + schunk;
  const bf16* bsrc = Bm + (size_t)(cb * 256 + w * 32 + (lane >> 2)) * 512 + schunk;
  char* adst = (char*)&As2[0] + w * 1024;
  char* bdst = (char*)&Bs2[0] + w * 2048;
  const int slot = g ^ ((li >> 1) & 3);

  f32x4 acc[4][4] = {};

  for (int kt = 0; kt < 16; ++kt) {
    __syncthreads();
    glds16(asrc + kt * 32, adst);
#pragma unroll
    for (int j = 0; j < 2; ++j)
      glds16(bsrc + (size_t)j * 16 * 512 + kt * 32, bdst + j * 1024);
    __syncthreads();
    bf16x8 af[4], bfr[4];
#pragma unroll
    for (int rt = 0; rt < 4; ++rt)
      af[rt] = *(const bf16x8*)&As2[(wr * 64 + rt * 16 + li) * 32 + slot * 8];
#pragma unroll
    for (int ct = 0; ct < 4; ++ct)
      bfr[ct] = *(const bf16x8*)&Bs2[(wc * 64 + ct * 16 + li) * 32 + slot * 8];
#pragma unroll
    for (int rt = 0; rt < 4; ++rt)
#pragma unroll
      for (int ct = 0; ct < 4; ++ct)
        acc[rt][ct] = MFMA16(af[rt], bfr[ct], acc[rt][ct]);
  }

  float bv[4];
#pragma unroll
  for (int ct = 0; ct < 4; ++ct) bv[ct] = bo[cb * 256 + wc * 64 + ct * 16 + li];
#pragma unroll
  for (int rt = 0; rt < 4; ++rt)
#pragma unroll
    for (int q = 0; q < 4; ++q) {
      float* op = out + (arow + wr * 64 + rt * 16 + g * 4 + q) * 512 + cb * 256 + wc * 64 + li;
      op[0]  = acc[rt][0][q] + bv[0];
      op[16] = acc[rt][1][q] + bv[1];
      op[32] = acc[rt][2][q] + bv[2];
      op[48] = acc[rt][3][q] + bv[3];
    }
}

// ---------------- host ----------------
extern "C" void kernel_launch(void* const* d_in, const int* in_sizes, int n_in,
                              void* d_out, int out_size, void* d_ws, size_t ws_size,
                              hipStream_t stream)
{
  const float* xq = (const float*)d_in[0];
  const float* xk = (const float*)d_in[1];
  const float* xv = (const float*)d_in[2];
  const float* Wq = (const float*)d_in[3];
  const float* Wk = (const float*)d_in[4];
  const float* Wv = (const float*)d_in[5];
  const float* Wo = (const float*)d_in[6];
  const float* bo = (const float*)d_in[7];
  float* out = (float*)d_out;

  char* ws = (char*)d_ws;
  const size_t WT_BYTES  = 512 * 512 * 2;           // 512 KiB each
  const size_t QKV_BYTES = (size_t)32768 * 512 * 2; // 32 MiB each
  bf16*  WqT = (bf16*)(ws);
  bf16*  WkT = (bf16*)(ws + WT_BYTES);
  bf16*  WvT = (bf16*)(ws + 2 * WT_BYTES);
  bf16*  WoT = (bf16*)(ws + 3 * WT_BYTES);
  bf16*  Qb  = (bf16*)(ws + 4 * WT_BYTES);
  bf16*  Kb  = (bf16*)(ws + 4 * WT_BYTES + QKV_BYTES);
  bf16*  Vb  = (bf16*)(ws + 4 * WT_BYTES + 2 * QKV_BYTES);
  float* kvp = (float*)(ws + 4 * WT_BYTES + 3 * QKV_BYTES);  // 8 MiB
  bf16*  WfT = Kb;  // overlay: Kb dead after k_kv

  k_prep  <<<dim3(8, 8, 4), 256, 0, stream>>>(Wq, Wk, Wv, Wo, WqT, WkT, WvT, WoT);
  k_qkv   <<<dim3(1536),    512, 0, stream>>>(xq, xk, xv, WqT, WkT, WvT, Qb, Kb, Vb);
  k_kv    <<<dim3(128, 4),  256, 0, stream>>>(Kb, Vb, kvp);
  k_wfused<<<dim3(128),     512, 0, stream>>>(kvp, WoT, WfT);
  k_out   <<<dim3(512),     512, 0, stream>>>(Qb, WfT, bo, out);
}